// Round 17
// baseline (40.311 us; speedup 1.0000x reference)
//
#include <hip/hip_runtime.h>
#include <hip/hip_fp16.h>
#include <math.h>

// f(x) = tanh-MLP(x), 1->16->32->32->16->3, per scalar element.
// R17 = R16 build (direct-global, wave-per-entry, neuron-per-lane) +
// element-major apply: each thread-iter loads ONE coalesced float4 of x
// (4 elements), does 12 conflict-free b32 LDS gathers (fp16 endpoint pairs,
// 3 channels x 4 elements, zero redundancy), and writes 3 nontemporal
// float4 stores (48B stride -- proven cost-free in R1 vs R6). Removes the
// out-major version's /3 index math, 16 scalar x loads/thread, 1.5x gather
// redundancy, and 8 cndmask selects per output.

#define TN 2048
#define XLO (-10.0f)
#define XHI (10.0f)

typedef float f32x4 __attribute__((ext_vector_type(4)));

__device__ __forceinline__ float fast_tanh(float x) {
    float t = __builtin_amdgcn_exp2f(x * 2.885390081777927f);
    return 1.0f - 2.0f * __builtin_amdgcn_rcpf(t + 1.0f);
}

__global__ __launch_bounds__(256) void build_table(
    const float* __restrict__ W0, const float* __restrict__ b0,
    const float* __restrict__ W1, const float* __restrict__ b1,
    const float* __restrict__ W2, const float* __restrict__ b2,
    const float* __restrict__ W3, const float* __restrict__ b3,
    const float* __restrict__ W4, const float* __restrict__ b4,
    unsigned* __restrict__ tab_g)
{
    const int t    = threadIdx.x;
    const int wave = t >> 6;
    const int half = (t >> 5) & 1;
    const int sub  = t & 31;
    const int s16  = (sub < 15) ? sub : 15;
    const int e    = blockIdx.x * 4 + wave;
    const int p    = min(e + half, TN - 1);

    const float h = (XHI - XLO) / (float)(TN - 1);
    const float x = XLO + (float)p * h;

    float act = fast_tanh(fmaf(x, W0[s16], b0[s16]));
    {
        float acc0 = b1[sub], acc1 = 0.f, acc2 = 0.f, acc3 = 0.f;
        #pragma unroll
        for (int k = 0; k < 16; k += 4) {
            float a0 = __shfl(act, k + 0, 32);
            float a1 = __shfl(act, k + 1, 32);
            float a2 = __shfl(act, k + 2, 32);
            float a3 = __shfl(act, k + 3, 32);
            acc0 = fmaf(a0, W1[(k + 0) * 32 + sub], acc0);
            acc1 = fmaf(a1, W1[(k + 1) * 32 + sub], acc1);
            acc2 = fmaf(a2, W1[(k + 2) * 32 + sub], acc2);
            acc3 = fmaf(a3, W1[(k + 3) * 32 + sub], acc3);
        }
        act = fast_tanh((acc0 + acc1) + (acc2 + acc3));
    }
    {
        float acc0 = b2[sub], acc1 = 0.f, acc2 = 0.f, acc3 = 0.f;
        #pragma unroll
        for (int k = 0; k < 32; k += 4) {
            float a0 = __shfl(act, k + 0, 32);
            float a1 = __shfl(act, k + 1, 32);
            float a2 = __shfl(act, k + 2, 32);
            float a3 = __shfl(act, k + 3, 32);
            acc0 = fmaf(a0, W2[(k + 0) * 32 + sub], acc0);
            acc1 = fmaf(a1, W2[(k + 1) * 32 + sub], acc1);
            acc2 = fmaf(a2, W2[(k + 2) * 32 + sub], acc2);
            acc3 = fmaf(a3, W2[(k + 3) * 32 + sub], acc3);
        }
        act = fast_tanh((acc0 + acc1) + (acc2 + acc3));
    }
    {
        float acc0 = b3[s16], acc1 = 0.f, acc2 = 0.f, acc3 = 0.f;
        #pragma unroll
        for (int k = 0; k < 32; k += 4) {
            float a0 = __shfl(act, k + 0, 32);
            float a1 = __shfl(act, k + 1, 32);
            float a2 = __shfl(act, k + 2, 32);
            float a3 = __shfl(act, k + 3, 32);
            acc0 = fmaf(a0, W3[(k + 0) * 16 + s16], acc0);
            acc1 = fmaf(a1, W3[(k + 1) * 16 + s16], acc1);
            acc2 = fmaf(a2, W3[(k + 2) * 16 + s16], acc2);
            acc3 = fmaf(a3, W3[(k + 3) * 16 + s16], acc3);
        }
        act = fast_tanh((acc0 + acc1) + (acc2 + acc3));
    }
    float o0 = b4[0], o1 = b4[1], o2 = b4[2];
    #pragma unroll
    for (int k = 0; k < 16; ++k) {
        float ak = __shfl(act, k, 32);
        o0 = fmaf(ak, W4[k * 3 + 0], o0);
        o1 = fmaf(ak, W4[k * 3 + 1], o1);
        o2 = fmaf(ak, W4[k * 3 + 2], o2);
    }
    o0 = fast_tanh(o0); o1 = fast_tanh(o1); o2 = fast_tanh(o2);

    float h0 = __shfl(o0, 32, 64);
    float h1 = __shfl(o1, 32, 64);
    float h2 = __shfl(o2, 32, 64);

    if ((t & 63) == 0) {
        __half2 p0 = __floats2half2_rn(o0, h0);   // .x=f(e), .y=f(e+1)
        __half2 p1 = __floats2half2_rn(o1, h1);
        __half2 p2 = __floats2half2_rn(o2, h2);
        tab_g[         e] = *reinterpret_cast<unsigned*>(&p0);
        tab_g[TN     + e] = *reinterpret_cast<unsigned*>(&p1);
        tab_g[2 * TN + e] = *reinterpret_cast<unsigned*>(&p2);
    }
}

__device__ __forceinline__ void lerp3s(
    const unsigned* __restrict__ t0, const unsigned* __restrict__ t1,
    const unsigned* __restrict__ t2, float inv_h, float x,
    float& y0, float& y1, float& y2)
{
    float xc = fminf(fmaxf(x, XLO), XHI);
    float f  = (xc - XLO) * inv_h;
    int i0 = (int)f;
    i0 = min(i0, TN - 2);
    float fr = f - (float)i0;
    unsigned e0 = t0[i0];
    unsigned e1 = t1[i0];
    unsigned e2 = t2[i0];
    float2 p0 = __half22float2(*reinterpret_cast<__half2*>(&e0));
    float2 p1 = __half22float2(*reinterpret_cast<__half2*>(&e1));
    float2 p2 = __half22float2(*reinterpret_cast<__half2*>(&e2));
    y0 = fmaf(fr, p0.y - p0.x, p0.x);
    y1 = fmaf(fr, p1.y - p1.x, p1.x);
    y2 = fmaf(fr, p2.y - p2.x, p2.x);
}

__global__ __launch_bounds__(256) void apply_e(
    const float4* __restrict__ x4, const unsigned* __restrict__ tab_g,
    float4* __restrict__ out4, unsigned n_units)
{
    __shared__ __align__(16) unsigned tab[3 * TN];
    {
        uint4* dst = (uint4*)tab;
        const uint4* src = (const uint4*)tab_g;
        for (int i = threadIdx.x; i < 3 * TN / 4; i += 256) dst[i] = src[i];
    }
    __syncthreads();
    const unsigned* t0 = tab;
    const unsigned* t1 = tab + TN;
    const unsigned* t2 = tab + 2 * TN;

    const float inv_h = (float)(TN - 1) / (XHI - XLO);
    unsigned stride = gridDim.x * 256u;
    for (unsigned u = blockIdx.x * 256u + threadIdx.x; u < n_units; u += stride) {
        float4 xv = x4[u];                    // one coalesced 16B load
        float a0, a1, a2, c0, c1, c2, d0, d1, d2, f0, f1, f2;
        lerp3s(t0, t1, t2, inv_h, xv.x, a0, a1, a2);
        lerp3s(t0, t1, t2, inv_h, xv.y, c0, c1, c2);
        lerp3s(t0, t1, t2, inv_h, xv.z, d0, d1, d2);
        lerp3s(t0, t1, t2, inv_h, xv.w, f0, f1, f2);
        f32x4 o0 = {a0, a1, a2, c0};
        f32x4 o1 = {c1, c2, d0, d1};
        f32x4 o2 = {d2, f0, f1, f2};
        f32x4* base = (f32x4*)(out4 + 3u * u);
        __builtin_nontemporal_store(o0, base + 0);
        __builtin_nontemporal_store(o1, base + 1);
        __builtin_nontemporal_store(o2, base + 2);
    }
}

extern "C" void kernel_launch(void* const* d_in, const int* in_sizes, int n_in,
                              void* d_out, int out_size, void* d_ws, size_t ws_size,
                              hipStream_t stream) {
    const float* x  = (const float*)d_in[0];
    const float* W0 = (const float*)d_in[1];
    const float* b0 = (const float*)d_in[2];
    const float* W1 = (const float*)d_in[3];
    const float* b1 = (const float*)d_in[4];
    const float* W2 = (const float*)d_in[5];
    const float* b2 = (const float*)d_in[6];
    const float* W3 = (const float*)d_in[7];
    const float* b3 = (const float*)d_in[8];
    const float* W4 = (const float*)d_in[9];
    const float* b4 = (const float*)d_in[10];
    unsigned* tab = (unsigned*)d_ws;   // 3*TN*4 = 24 KB scratch

    build_table<<<TN / 4, 256, 0, stream>>>(
        W0, b0, W1, b1, W2, b2, W3, b3, W4, b4, tab);

    unsigned n_units = (unsigned)in_sizes[0] / 4u;   // 1048576 float4 chunks
    int blocks = 1536;                               // 6 blocks/CU (24KB LDS)
    apply_e<<<blocks, 256, 0, stream>>>(
        (const float4*)x, tab, (float4*)d_out, n_units);
}

// Round 18
// 22.448 us; speedup vs baseline: 1.7958x; 1.7958x over previous
//
#include <hip/hip_runtime.h>
#include <hip/hip_fp16.h>
#include <math.h>

// f(x) = tanh-MLP(x), 1->16->32->32->16->3, per scalar element.
// R18 = R16 verbatim (best: 22.57us). R17's element-major apply regressed
// to 40us: NONTEMPORAL stores at 48B lane stride defeat L2 write-combining
// -> partial-line HBM writes -> ~3x write amplification. Rule: nt stores
// only for wave-contiguous streams (as in apply_s below).
// Budget: apply ~12.5us (floor 10.6), build ~3us, fixed 2-dispatch graph
// overhead ~5-6us. Fused-kernel alternatives bottomed at 33.5us (R14).

#define TN 2048
#define XLO (-10.0f)
#define XHI (10.0f)

typedef float f32x4 __attribute__((ext_vector_type(4)));

__device__ __forceinline__ float fast_tanh(float x) {
    float t = __builtin_amdgcn_exp2f(x * 2.885390081777927f);
    return 1.0f - 2.0f * __builtin_amdgcn_rcpf(t + 1.0f);
}

__global__ __launch_bounds__(256) void build_table(
    const float* __restrict__ W0, const float* __restrict__ b0,
    const float* __restrict__ W1, const float* __restrict__ b1,
    const float* __restrict__ W2, const float* __restrict__ b2,
    const float* __restrict__ W3, const float* __restrict__ b3,
    const float* __restrict__ W4, const float* __restrict__ b4,
    unsigned* __restrict__ tab_g)
{
    const int t    = threadIdx.x;
    const int wave = t >> 6;                  // 0..3
    const int half = (t >> 5) & 1;            // 0: point e, 1: point e+1
    const int sub  = t & 31;                  // neuron lane
    const int s16  = (sub < 15) ? sub : 15;
    const int e    = blockIdx.x * 4 + wave;   // entry index, < TN
    const int p    = min(e + half, TN - 1);

    const float h = (XHI - XLO) / (float)(TN - 1);
    const float x = XLO + (float)p * h;

    // L0: 1 -> 16 (coalesced reads, half-wave broadcast)
    float act = fast_tanh(fmaf(x, W0[s16], b0[s16]));

    // L1: 16 -> 32 (4-way ILP; W loads act-independent -> hoisted)
    {
        float acc0 = b1[sub], acc1 = 0.f, acc2 = 0.f, acc3 = 0.f;
        #pragma unroll
        for (int k = 0; k < 16; k += 4) {
            float a0 = __shfl(act, k + 0, 32);
            float a1 = __shfl(act, k + 1, 32);
            float a2 = __shfl(act, k + 2, 32);
            float a3 = __shfl(act, k + 3, 32);
            acc0 = fmaf(a0, W1[(k + 0) * 32 + sub], acc0);
            acc1 = fmaf(a1, W1[(k + 1) * 32 + sub], acc1);
            acc2 = fmaf(a2, W1[(k + 2) * 32 + sub], acc2);
            acc3 = fmaf(a3, W1[(k + 3) * 32 + sub], acc3);
        }
        act = fast_tanh((acc0 + acc1) + (acc2 + acc3));
    }
    // L2: 32 -> 32
    {
        float acc0 = b2[sub], acc1 = 0.f, acc2 = 0.f, acc3 = 0.f;
        #pragma unroll
        for (int k = 0; k < 32; k += 4) {
            float a0 = __shfl(act, k + 0, 32);
            float a1 = __shfl(act, k + 1, 32);
            float a2 = __shfl(act, k + 2, 32);
            float a3 = __shfl(act, k + 3, 32);
            acc0 = fmaf(a0, W2[(k + 0) * 32 + sub], acc0);
            acc1 = fmaf(a1, W2[(k + 1) * 32 + sub], acc1);
            acc2 = fmaf(a2, W2[(k + 2) * 32 + sub], acc2);
            acc3 = fmaf(a3, W2[(k + 3) * 32 + sub], acc3);
        }
        act = fast_tanh((acc0 + acc1) + (acc2 + acc3));
    }
    // L3: 32 -> 16
    {
        float acc0 = b3[s16], acc1 = 0.f, acc2 = 0.f, acc3 = 0.f;
        #pragma unroll
        for (int k = 0; k < 32; k += 4) {
            float a0 = __shfl(act, k + 0, 32);
            float a1 = __shfl(act, k + 1, 32);
            float a2 = __shfl(act, k + 2, 32);
            float a3 = __shfl(act, k + 3, 32);
            acc0 = fmaf(a0, W3[(k + 0) * 16 + s16], acc0);
            acc1 = fmaf(a1, W3[(k + 1) * 16 + s16], acc1);
            acc2 = fmaf(a2, W3[(k + 2) * 16 + s16], acc2);
            acc3 = fmaf(a3, W3[(k + 3) * 16 + s16], acc3);
        }
        act = fast_tanh((acc0 + acc1) + (acc2 + acc3));
    }
    // L4: 16 -> 3 (uniform addresses -> scalar broadcasts)
    float o0 = b4[0], o1 = b4[1], o2 = b4[2];
    #pragma unroll
    for (int k = 0; k < 16; ++k) {
        float ak = __shfl(act, k, 32);
        o0 = fmaf(ak, W4[k * 3 + 0], o0);
        o1 = fmaf(ak, W4[k * 3 + 1], o1);
        o2 = fmaf(ak, W4[k * 3 + 2], o2);
    }
    o0 = fast_tanh(o0); o1 = fast_tanh(o1); o2 = fast_tanh(o2);

    // lane 32 holds point e+1's outputs
    float h0 = __shfl(o0, 32, 64);
    float h1 = __shfl(o1, 32, 64);
    float h2 = __shfl(o2, 32, 64);

    if ((t & 63) == 0) {
        __half2 p0 = __floats2half2_rn(o0, h0);   // .x=f(e), .y=f(e+1)
        __half2 p1 = __floats2half2_rn(o1, h1);
        __half2 p2 = __floats2half2_rn(o2, h2);
        tab_g[         e] = *reinterpret_cast<unsigned*>(&p0);
        tab_g[TN     + e] = *reinterpret_cast<unsigned*>(&p1);
        tab_g[2 * TN + e] = *reinterpret_cast<unsigned*>(&p2);
    }
}

__device__ __forceinline__ void lerp3s(
    const unsigned* __restrict__ t0, const unsigned* __restrict__ t1,
    const unsigned* __restrict__ t2, float inv_h, float x,
    float& y0, float& y1, float& y2)
{
    float xc = fminf(fmaxf(x, XLO), XHI);
    float f  = (xc - XLO) * inv_h;
    int i0 = (int)f;
    i0 = min(i0, TN - 2);
    float fr = f - (float)i0;
    unsigned e0 = t0[i0];
    unsigned e1 = t1[i0];
    unsigned e2 = t2[i0];
    float2 p0 = __half22float2(*reinterpret_cast<__half2*>(&e0));
    float2 p1 = __half22float2(*reinterpret_cast<__half2*>(&e1));
    float2 p2 = __half22float2(*reinterpret_cast<__half2*>(&e2));
    y0 = fmaf(fr, p0.y - p0.x, p0.x);
    y1 = fmaf(fr, p1.y - p1.x, p1.x);
    y2 = fmaf(fr, p2.y - p2.x, p2.x);
}

__global__ __launch_bounds__(256) void apply_s(
    const float* __restrict__ x, const unsigned* __restrict__ tab_g,
    float4* __restrict__ out4, unsigned n_out4)
{
    __shared__ __align__(16) unsigned tab[3 * TN];
    {
        uint4* dst = (uint4*)tab;
        const uint4* src = (const uint4*)tab_g;
        for (int i = threadIdx.x; i < 3 * TN / 4; i += 256) dst[i] = src[i];
    }
    __syncthreads();
    const unsigned* t0 = tab;
    const unsigned* t1 = tab + TN;
    const unsigned* t2 = tab + 2 * TN;

    const float inv_h = (float)(TN - 1) / (XHI - XLO);
    unsigned stride = gridDim.x * 256u;
    for (unsigned g = blockIdx.x * 256u + threadIdx.x; g < n_out4; g += stride) {
        unsigned e = (4u * g) / 3u;          // first input element needed
        unsigned r = 4u * g - 3u * e;        // 0,1,2
        float x0 = x[e];
        float x1 = x[e + 1];
        float s0, s1, s2, s3, s4, s5;
        lerp3s(t0, t1, t2, inv_h, x0, s0, s1, s2);
        lerp3s(t0, t1, t2, inv_h, x1, s3, s4, s5);
        f32x4 o;
        o.x = (r == 0u) ? s0 : ((r == 1u) ? s1 : s2);
        o.y = (r == 0u) ? s1 : ((r == 1u) ? s2 : s3);
        o.z = (r == 0u) ? s2 : ((r == 1u) ? s3 : s4);
        o.w = (r == 0u) ? s3 : ((r == 1u) ? s4 : s5);
        // wave-contiguous stream -> nontemporal is safe and saves L2 churn
        __builtin_nontemporal_store(o, (f32x4*)(out4 + g));
    }
}

extern "C" void kernel_launch(void* const* d_in, const int* in_sizes, int n_in,
                              void* d_out, int out_size, void* d_ws, size_t ws_size,
                              hipStream_t stream) {
    const float* x  = (const float*)d_in[0];
    const float* W0 = (const float*)d_in[1];
    const float* b0 = (const float*)d_in[2];
    const float* W1 = (const float*)d_in[3];
    const float* b1 = (const float*)d_in[4];
    const float* W2 = (const float*)d_in[5];
    const float* b2 = (const float*)d_in[6];
    const float* W3 = (const float*)d_in[7];
    const float* b3 = (const float*)d_in[8];
    const float* W4 = (const float*)d_in[9];
    const float* b4 = (const float*)d_in[10];
    unsigned* tab = (unsigned*)d_ws;   // 3*TN*4 = 24 KB scratch

    build_table<<<TN / 4, 256, 0, stream>>>(
        W0, b0, W1, b1, W2, b2, W3, b3, W4, b4, tab);

    unsigned n_out4 = (unsigned)out_size / 4u;   // 3145728
    int blocks = 1536;                           // 6 blocks/CU (24KB LDS)
    apply_s<<<blocks, 256, 0, stream>>>(
        x, tab, (float4*)d_out, n_out4);
}